// Round 3
// baseline (156.918 us; speedup 1.0000x reference)
//
#include <hip/hip_runtime.h>

// ---------------- types / helpers ----------------
typedef unsigned short u16;
typedef float f32x4 __attribute__((ext_vector_type(4)));
typedef short bf16x8 __attribute__((ext_vector_type(8)));
typedef u16 u16x4 __attribute__((ext_vector_type(4)));

__device__ __forceinline__ u16 f2bf(float f) {
    unsigned u = __float_as_uint(f);
    u = (u + 0x7FFFu + ((u >> 16) & 1u)) >> 16;
    return (u16)u;
}

#define LOG2E 1.4426950408889634f

#if __has_builtin(__builtin_amdgcn_exp2f)
__device__ __forceinline__ float exp2_fast(float x) { return __builtin_amdgcn_exp2f(x); }
#else
__device__ __forceinline__ float exp2_fast(float x) { return __expf(x * 0.6931471805599453f); }
#endif

__device__ __forceinline__ unsigned pack2bf(float a, float b) {
    unsigned ua = __float_as_uint(a) + 0x8000u;
    unsigned ub = __float_as_uint(b) + 0x8000u;
#if __has_builtin(__builtin_amdgcn_perm)
    return __builtin_amdgcn_perm(ub, ua, 0x07060302u);
#else
    return ((ua >> 16) & 0xFFFFu) | (ub & 0xFFFF0000u);
#endif
}

#if __has_builtin(__builtin_amdgcn_cvt_pk_bf16_f32)
typedef __bf16 bf2_t __attribute__((ext_vector_type(2)));
__device__ __forceinline__ unsigned cvtpk(float a, float b) {
    bf2_t r = __builtin_amdgcn_cvt_pk_bf16_f32(a, b);
    return __builtin_bit_cast(unsigned, r);
}
#else
__device__ __forceinline__ unsigned cvtpk(float a, float b) { return pack2bf(a, b); }
#endif

__device__ __forceinline__ bf16x8 bc8(uint4 u) { return __builtin_bit_cast(bf16x8, u); }

// async 16B/lane global->LDS DMA; lds dst = wave-uniform base + lane*16.
#if __has_builtin(__builtin_amdgcn_global_load_lds)
typedef const __attribute__((address_space(1))) void* as1cv;
typedef __attribute__((address_space(3))) void* as3v;
__device__ __forceinline__ void dma16(const void* g, void* lds_base, int lane) {
    __builtin_amdgcn_global_load_lds((as1cv)g, (as3v)lds_base, 16, 0, 0);
}
#else
__device__ __forceinline__ void dma16(const void* g, void* lds_base, int lane) {
    *(uint4*)((char*)lds_base + lane * 16) = *(const uint4*)g;
}
#endif

// Problem constants. DEDUP: reflect-pad duplicates keys; only 3136 unique
// source pixels, multiplicity c in {1,2,4} folded into energy as +log2(c).
#define BB 2
#define HH 56
#define SQ 3136
#define SKP 3200          // padded unique keys (25 rounds x 128); [3136,3200) masked
#define VT_STRIDE 3200

// workspace offsets (u16 units); total 5,052,672 u16 = 10.1 MB
#define WS_Q    0         // 6272*256
#define WS_K    1605632   // 6272*256
#define WS_VT   3211264   // 512*3200
#define WS_WT   4849664   // 3*65536 fragment-packed weights
#define WS_CB   5046272   // 3200 floats (log2 multiplicity bias; -1e4 for pad)

// ---------------- kernel 0: weight fragment-pack + cbias + VT pad zero -------------
// wtf[mode][f=((nz*8+s)*8+nt)][L=quad*16+l16][j=0..7]
//   = W_mode[k=s*32+quad*8+j][d=nz*128+nt*16+l16] * (mode==0 ? LOG2E : 1)
// grid (4 kx, 4 dx, 3 mode): 64x64 tile, coalesced float4 load + LDS transpose.
__global__ __launch_bounds__(256) void wprep_kernel(const float* __restrict__ Wq,
                                                    const float* __restrict__ Wk,
                                                    const float* __restrict__ Wv,
                                                    u16* __restrict__ wtf,
                                                    u16* __restrict__ vtb,
                                                    float* __restrict__ cb) {
    __shared__ u16 T[64][68];
    int mode = blockIdx.z;
    const float* W = (mode == 0) ? Wq : ((mode == 1) ? Wk : Wv);
    float sc = (mode == 0) ? LOG2E : 1.0f;
    int kx = blockIdx.x * 64, dx = blockIdx.y * 64;
    int tid = threadIdx.x;
    int r16 = tid >> 4, c4 = (tid & 15) * 4;
#pragma unroll
    for (int p = 0; p < 4; ++p) {
        int kr = p * 16 + r16;
        float4 f = *(const float4*)&W[(size_t)(kx + kr) * 256 + dx + c4];
        T[kr][c4 + 0] = f2bf(f.x * sc);
        T[kr][c4 + 1] = f2bf(f.y * sc);
        T[kr][c4 + 2] = f2bf(f.z * sc);
        T[kr][c4 + 3] = f2bf(f.w * sc);
    }
    __syncthreads();
    int l16 = tid & 15, nt_loc = (tid >> 4) & 3, quad = (tid >> 6) & 3;
#pragma unroll
    for (int s_loc = 0; s_loc < 2; ++s_loc) {
        int k0 = s_loc * 32 + quad * 8;
        int d_loc = nt_loc * 16 + l16;
        u16 tmp[8];
#pragma unroll
        for (int j = 0; j < 8; ++j) tmp[j] = T[k0 + j][d_loc];
        int d = dx + d_loc;
        int nz = d >> 7, ntg = (d >> 4) & 7;
        int s = (kx >> 5) + s_loc;
        int f = (nz * 8 + s) * 8 + ntg;
        int L = quad * 16 + l16;
        *(uint4*)&wtf[(size_t)mode * 65536 + (size_t)f * 512 + (size_t)L * 8] = *(uint4*)tmp;
    }
    // chores
    if (mode == 1 && kx == 0 && dx == 0) {
        for (int i = tid; i < SKP; i += 256) {
            float v;
            if (i < SQ) {
                int rr = i / 56, cc = i - rr * 56;
                float a = ((rr >= 1 && rr <= 3) || (rr >= 52 && rr <= 54)) ? 1.f : 0.f;
                float b2 = ((cc >= 1 && cc <= 3) || (cc >= 52 && cc <= 54)) ? 1.f : 0.f;
                v = a + b2;
            } else v = -10000.f;
            cb[i] = v;
        }
    }
    if (mode == 2 && kx == 0 && dx == 0) {
        for (int i = tid; i < 512 * 8; i += 256) {
            int row = i >> 3, c16 = i & 7;
            *(uint4*)&vtb[(size_t)row * VT_STRIDE + SQ + c16 * 8] = (uint4){0, 0, 0, 0};
        }
    }
}

// ---------------- kernel 1: projections (dedup: all modes project same 6272 rows) ---
// grid (98, 3 modes, 2 nz). modes 0/1 (Q/K): SWAPPED MFMA operands -> per-lane
// output is row-major [xrow][c] -> packed uint2 stores. mode 2 (V^T): original
// orientation -> [c][kp] paired stores.
__global__ __launch_bounds__(256, 4) void proj_kernel(const float* __restrict__ x,
                                                      const u16* __restrict__ wtf,
                                                      const float* __restrict__ bq,
                                                      const float* __restrict__ bk,
                                                      const float* __restrict__ bv,
                                                      u16* __restrict__ qout,
                                                      u16* __restrict__ kout,
                                                      u16* __restrict__ vtout) {
    int mode = blockIdx.y, nz = blockIdx.z;
    int mbase = blockIdx.x * 64;
    int tid = threadIdx.x;
    int wave = tid >> 6, quad = (tid >> 4) & 3, l16 = tid & 15;
    const float* bias = (mode == 0) ? bq : ((mode == 1) ? bk : bv);
    float wsc = (mode == 0) ? LOG2E : 1.0f;
    const u16* wf = wtf + (size_t)mode * 65536 + (size_t)nz * 32768 + (size_t)(quad * 16 + l16) * 8;

    int m_a = mbase + wave * 16 + l16;          // x row (identity for all modes now)
    const float* xr = x + (size_t)m_a * 256;

    f32x4 acc[8];
#pragma unroll
    for (int i = 0; i < 8; i++) acc[i] = (f32x4){0.f, 0.f, 0.f, 0.f};

#pragma unroll
    for (int s = 0; s < 8; ++s) {
        float4 f0 = *(const float4*)&xr[s * 32 + quad * 8];
        float4 f1 = *(const float4*)&xr[s * 32 + quad * 8 + 4];
        uint4 aw = (uint4){pack2bf(f0.x, f0.y), pack2bf(f0.z, f0.w),
                           pack2bf(f1.x, f1.y), pack2bf(f1.z, f1.w)};
        bf16x8 af = bc8(aw);
        if (mode == 2) {
#pragma unroll
            for (int nt = 0; nt < 8; nt++) {
                bf16x8 bfrag = *(const bf16x8*)&wf[(s * 8 + nt) * 512];
                acc[nt] = __builtin_amdgcn_mfma_f32_16x16x32_bf16(af, bfrag, acc[nt], 0, 0, 0);
            }
        } else {
#pragma unroll
            for (int nt = 0; nt < 8; nt++) {
                bf16x8 bfrag = *(const bf16x8*)&wf[(s * 8 + nt) * 512];
                acc[nt] = __builtin_amdgcn_mfma_f32_16x16x32_bf16(bfrag, af, acc[nt], 0, 0, 0);
            }
        }
    }

    if (mode == 2) {
        int mrow_base = mbase + wave * 16 + quad * 4;
#pragma unroll
        for (int nt = 0; nt < 8; nt++) {
            int c = nz * 128 + nt * 16 + l16;
            float bvv = bias[c];
#pragma unroll
            for (int p = 0; p < 4; p += 2) {
                int m = mrow_base + p;
                int bb = (m >= SQ) ? 1 : 0;
                int kp = m - bb * SQ;
                unsigned pk = pack2bf(acc[nt][p] + bvv, acc[nt][p + 1] + bvv);
                *(unsigned*)&vtout[(size_t)(bb * 256 + c) * VT_STRIDE + kp] = pk;
            }
        }
    } else {
        u16* outp = (mode == 0) ? qout : kout;
#pragma unroll
        for (int nt = 0; nt < 8; nt++) {
            int c0 = nz * 128 + nt * 16 + quad * 4;
            float4 b4 = *(const float4*)&bias[c0];
            float v0 = acc[nt][0] + b4.x * wsc;
            float v1 = acc[nt][1] + b4.y * wsc;
            float v2 = acc[nt][2] + b4.z * wsc;
            float v3 = acc[nt][3] + b4.w * wsc;
            uint2 pk = (uint2){pack2bf(v0, v1), pack2bf(v2, v3)};
            *(uint2*)&outp[((size_t)m_a << 8) + c0] = pk;
        }
    }
}

// ---------------- kernel 2: flash attention (dedup keys, bias-in-C, barrier-free) ---
// grid (16 bh, 49 qsub). 25 uniform rounds x 128 keys (3200 padded; pad masked by
// cbias=-1e4 -> p=0 exactly, NO tail branch). Energy bias log2(c) enters as the
// QK MFMA C-operand (free). Denominator via ones-B PV MFMA -> lv[i][r] already
// aligned with output rows (no shuffles). Barrier-free 3-buf DMA pipeline.
__global__ __launch_bounds__(256, 3) void attn_kernel(const u16* __restrict__ qb,
                                                      const u16* __restrict__ kb,
                                                      const u16* __restrict__ vtb,
                                                      const float* __restrict__ cb,
                                                      const float* __restrict__ x,
                                                      const float* __restrict__ gammap,
                                                      float* __restrict__ out) {
    __shared__ __align__(16) u16 S[24576];   // buf b at b*8192 u16: K +0, V +4096

    int tid = threadIdx.x;
    int th = tid >> 6, lane = tid & 63, quad = lane >> 4, l16 = lane & 15;
    int bh = blockIdx.x;
    int b = bh >> 3, h = bh & 7;
    int qsub = blockIdx.y * 64;

    bf16x8 qf[4];
#pragma unroll
    for (int i = 0; i < 4; ++i)
        qf[i] = *(const bf16x8*)&qb[((size_t)(b * SQ + qsub + i * 16 + l16) << 8) + h * 32 + quad * 8];

    const u16* kg = kb + ((size_t)(b * SQ) << 8) + h * 32;
    const u16* vg = vtb + (size_t)(b * 256 + h * 32) * VT_STRIDE;

    f32x4 o[4][2], lv[4];
#pragma unroll
    for (int i = 0; i < 4; ++i) {
        o[i][0] = (f32x4){0.f, 0.f, 0.f, 0.f};
        o[i][1] = (f32x4){0.f, 0.f, 0.f, 0.f};
        lv[i]   = (f32x4){0.f, 0.f, 0.f, 0.f};
    }
    short ov = (short)0x3F80;
    bf16x8 ones8 = {ov, ov, ov, ov, ov, ov, ov, ov};

    auto stage = [&](int r_ch, int buf) {
        u16* base = &S[buf * 8192];
        int kbase = r_ch * 128;
#pragma unroll
        for (int i = 0; i < 2; ++i) {
            int g = th + i * 4;
            int grow = kbase + g * 16 + (lane & 15);
            if (grow > SQ - 1) grow = SQ - 1;
            dma16(kg + ((size_t)grow << 8) + (lane >> 4) * 8, base + g * 512, lane);
            int col = kbase + (2 * g + (lane >> 5)) * 8;
            dma16(vg + (size_t)(lane & 31) * VT_STRIDE + col, base + 4096 + g * 512, lane);
        }
    };

    int tA = th, tB = th + 4;
    int vOffA = tA * 512 + (((quad >> 1) * 32 + l16) << 3) + (quad & 1) * 4;
    int vOffB = tB * 512 + (((quad >> 1) * 32 + l16) << 3) + (quad & 1) * 4;

    auto round_body = [&](int r, int bR) {
        const u16* Kl = &S[bR * 8192];
        const u16* Vl = Kl + 4096;
        bf16x8 kfA = *(const bf16x8*)&Kl[tA * 512 + lane * 8];
        bf16x8 kfB = *(const bf16x8*)&Kl[tB * 512 + lane * 8];
        // per-key log2(multiplicity) bias -> MFMA C operand (rows quad*4..+3)
        f32x4 cfA = __builtin_bit_cast(f32x4, *(const float4*)&cb[r * 128 + tA * 16 + quad * 4]);
        f32x4 cfB = __builtin_bit_cast(f32x4, *(const float4*)&cb[r * 128 + tB * 16 + quad * 4]);
        uint2 wA0 = *(const uint2*)&Vl[vOffA];
        uint2 wB0 = *(const uint2*)&Vl[vOffB];
        uint2 wA1 = *(const uint2*)&Vl[vOffA + 128];
        uint2 wB1 = *(const uint2*)&Vl[vOffB + 128];
        bf16x8 V0 = bc8((uint4){wA0.x, wA0.y, wB0.x, wB0.y});
        bf16x8 V1 = bc8((uint4){wA1.x, wA1.y, wB1.x, wB1.y});

        f32x4 eA[4], eB[4];
#pragma unroll
        for (int i = 0; i < 4; ++i)
            eA[i] = __builtin_amdgcn_mfma_f32_16x16x32_bf16(kfA, qf[i], cfA, 0, 0, 0);
#pragma unroll
        for (int i = 0; i < 4; ++i)
            eB[i] = __builtin_amdgcn_mfma_f32_16x16x32_bf16(kfB, qf[i], cfB, 0, 0, 0);

#pragma unroll
        for (int i = 0; i < 4; ++i) {
            float pA0 = exp2_fast(eA[i][0]), pA1 = exp2_fast(eA[i][1]);
            float pA2 = exp2_fast(eA[i][2]), pA3 = exp2_fast(eA[i][3]);
            float pB0 = exp2_fast(eB[i][0]), pB1 = exp2_fast(eB[i][1]);
            float pB2 = exp2_fast(eB[i][2]), pB3 = exp2_fast(eB[i][3]);
            bf16x8 pa = bc8((uint4){cvtpk(pA0, pA1), cvtpk(pA2, pA3),
                                    cvtpk(pB0, pB1), cvtpk(pB2, pB3)});
            o[i][0] = __builtin_amdgcn_mfma_f32_16x16x32_bf16(pa, V0, o[i][0], 0, 0, 0);
            o[i][1] = __builtin_amdgcn_mfma_f32_16x16x32_bf16(pa, V1, o[i][1], 0, 0, 0);
            lv[i]   = __builtin_amdgcn_mfma_f32_16x16x32_bf16(pa, ones8, lv[i], 0, 0, 0);
        }
    };

    stage(0, 0);
    stage(1, 1);
    int bR = 0, bS = 2;
    for (int r = 0; r < 24; ++r) {
        asm volatile("s_waitcnt vmcnt(4)" ::: "memory");   // round r's DMAs done
        if (r + 2 < 25) stage(r + 2, bS);
        round_body(r, bR);
        bR = (bR == 2) ? 0 : bR + 1;
        bS = (bS == 2) ? 0 : bS + 1;
    }
    asm volatile("s_waitcnt vmcnt(0)" ::: "memory");
    round_body(24, bR);                        // 24 % 3 == 0

    __syncthreads();                           // all waves done; LDS reusable

    // ---- two-stage merge of 4 t-quarters via LDS ----
    float* mg = (float*)&S[0];
    {
        int slot = ((th & 1) * 64 + lane) * 48;
        if (th >= 2) {
#pragma unroll
            for (int i = 0; i < 4; ++i) {
                *(f32x4*)&mg[slot + i * 8]      = o[i][0];
                *(f32x4*)&mg[slot + i * 8 + 4]  = o[i][1];
                *(f32x4*)&mg[slot + 32 + i * 4] = lv[i];
            }
        }
        __syncthreads();
        if (th < 2) {
#pragma unroll
            for (int i = 0; i < 4; ++i) {
                o[i][0] += *(const f32x4*)&mg[slot + i * 8];
                o[i][1] += *(const f32x4*)&mg[slot + i * 8 + 4];
                lv[i]   += *(const f32x4*)&mg[slot + 32 + i * 4];
            }
        }
        __syncthreads();
    }
    {
        int slot = lane * 48;
        if (th == 1) {
#pragma unroll
            for (int i = 0; i < 4; ++i) {
                *(f32x4*)&mg[slot + i * 8]      = o[i][0];
                *(f32x4*)&mg[slot + i * 8 + 4]  = o[i][1];
                *(f32x4*)&mg[slot + 32 + i * 4] = lv[i];
            }
        }
        __syncthreads();
        if (th == 0) {
            float g = gammap[0];
#pragma unroll
            for (int i = 0; i < 4; ++i) {
                o[i][0] += *(const f32x4*)&mg[slot + i * 8];
                o[i][1] += *(const f32x4*)&mg[slot + i * 8 + 4];
                lv[i]   += *(const f32x4*)&mg[slot + 32 + i * 4];
#pragma unroll
                for (int r2 = 0; r2 < 4; ++r2) {
                    float scl = g / lv[i][r2];     // lv row-aligned with output rows
                    int q = qsub + i * 16 + quad * 4 + r2;
                    size_t base = ((size_t)(b * SQ + q) << 8) + h * 32 + l16;
                    out[base]      = o[i][0][r2] * scl + x[base];
                    out[base + 16] = o[i][1][r2] * scl + x[base + 16];
                }
            }
        }
    }
}

// ---------------- launcher ----------------
extern "C" void kernel_launch(void* const* d_in, const int* in_sizes, int n_in,
                              void* d_out, int out_size, void* d_ws, size_t ws_size,
                              hipStream_t stream) {
    const float* x     = (const float*)d_in[0];
    const float* Wq    = (const float*)d_in[1];
    const float* bq    = (const float*)d_in[2];
    const float* Wk    = (const float*)d_in[3];
    const float* bk    = (const float*)d_in[4];
    const float* Wv    = (const float*)d_in[5];
    const float* bv    = (const float*)d_in[6];
    const float* gamma = (const float*)d_in[7];
    float* out = (float*)d_out;

    u16* ws   = (u16*)d_ws;
    u16* qbuf = ws + WS_Q;
    u16* kbuf = ws + WS_K;
    u16* vtb  = ws + WS_VT;
    u16* wtf  = ws + WS_WT;
    float* cbias = (float*)(ws + WS_CB);

    wprep_kernel<<<dim3(4, 4, 3), 256, 0, stream>>>(Wq, Wk, Wv, wtf, vtb, cbias);
    proj_kernel<<<dim3(98, 3, 2), 256, 0, stream>>>(x, wtf, bq, bk, bv, qbuf, kbuf, vtb);
    attn_kernel<<<dim3(16, 49), 256, 0, stream>>>(qbuf, kbuf, vtb, cbias, x, gamma, out);
}

// Round 4
// 150.122 us; speedup vs baseline: 1.0453x; 1.0453x over previous
//
#include <hip/hip_runtime.h>

// ---------------- types / helpers ----------------
typedef unsigned short u16;
typedef float f32x4 __attribute__((ext_vector_type(4)));
typedef short bf16x8 __attribute__((ext_vector_type(8)));
typedef u16 u16x4 __attribute__((ext_vector_type(4)));

__device__ __forceinline__ u16 f2bf(float f) {
    unsigned u = __float_as_uint(f);
    u = (u + 0x7FFFu + ((u >> 16) & 1u)) >> 16;
    return (u16)u;
}

#define LOG2E 1.4426950408889634f

#if __has_builtin(__builtin_amdgcn_exp2f)
__device__ __forceinline__ float exp2_fast(float x) { return __builtin_amdgcn_exp2f(x); }
#else
__device__ __forceinline__ float exp2_fast(float x) { return __expf(x * 0.6931471805599453f); }
#endif

__device__ __forceinline__ unsigned pack2bf(float a, float b) {
    unsigned ua = __float_as_uint(a) + 0x8000u;
    unsigned ub = __float_as_uint(b) + 0x8000u;
#if __has_builtin(__builtin_amdgcn_perm)
    return __builtin_amdgcn_perm(ub, ua, 0x07060302u);
#else
    return ((ua >> 16) & 0xFFFFu) | (ub & 0xFFFF0000u);
#endif
}

#if __has_builtin(__builtin_amdgcn_cvt_pk_bf16_f32)
typedef __bf16 bf2_t __attribute__((ext_vector_type(2)));
__device__ __forceinline__ unsigned cvtpk(float a, float b) {
    bf2_t r = __builtin_amdgcn_cvt_pk_bf16_f32(a, b);
    return __builtin_bit_cast(unsigned, r);
}
#else
__device__ __forceinline__ unsigned cvtpk(float a, float b) { return pack2bf(a, b); }
#endif

__device__ __forceinline__ bf16x8 bc8(uint4 u) { return __builtin_bit_cast(bf16x8, u); }

// async 16B/lane global->LDS DMA; lds dst = wave-uniform base + lane*16.
#if __has_builtin(__builtin_amdgcn_global_load_lds)
typedef const __attribute__((address_space(1))) void* as1cv;
typedef __attribute__((address_space(3))) void* as3v;
__device__ __forceinline__ void dma16(const void* g, void* lds_base, int lane) {
    __builtin_amdgcn_global_load_lds((as1cv)g, (as3v)lds_base, 16, 0, 0);
}
#else
__device__ __forceinline__ void dma16(const void* g, void* lds_base, int lane) {
    *(uint4*)((char*)lds_base + lane * 16) = *(const uint4*)g;
}
#endif

// Problem constants. DEDUP: reflect-pad duplicates keys; only 3136 unique source
// pixels. Multiplicity c in {1,2,4} is folded into the DATA: V^T columns are
// pre-scaled by c (exact: powers of 2), and the softmax denominator uses a
// counts-vector MFMA (crow[key] = bf16(c), 0 for pad) — so the attention loop
// has NO per-round global loads and NO tail branches.
#define BB 2
#define HH 56
#define SQ 3136
#define SKP 3200          // padded unique keys (25 rounds x 128); [3136,3200) c=0
#define VT_STRIDE 3200
#define CROWN 3584        // crow entries incl. DMA-overread pad

// workspace offsets (u16 units)
#define WS_Q    0         // 6272*256
#define WS_K    1605632   // 6272*256
#define WS_VT   3211264   // 512*3200
#define WS_WT   4849664   // 3*65536 fragment-packed weights
#define WS_CB   5046272   // 3584 u16: bf16 counts row

// ---------------- kernel 0: weight fragment-pack + crow + VT pad zero -------------
// wtf[mode][f=((nz*8+s)*8+nt)][L=quad*16+l16][j=0..7]
//   = W_mode[k=s*32+quad*8+j][d=nz*128+nt*16+l16] * (mode==0 ? LOG2E : 1)
// grid (4 kx, 4 dx, 3 mode): 64x64 tile, coalesced float4 load + LDS transpose.
__global__ __launch_bounds__(256) void wprep_kernel(const float* __restrict__ Wq,
                                                    const float* __restrict__ Wk,
                                                    const float* __restrict__ Wv,
                                                    u16* __restrict__ wtf,
                                                    u16* __restrict__ vtb,
                                                    u16* __restrict__ crow) {
    __shared__ u16 T[64][68];
    int mode = blockIdx.z;
    const float* W = (mode == 0) ? Wq : ((mode == 1) ? Wk : Wv);
    float sc = (mode == 0) ? LOG2E : 1.0f;
    int kx = blockIdx.x * 64, dx = blockIdx.y * 64;
    int tid = threadIdx.x;
    int r16 = tid >> 4, c4 = (tid & 15) * 4;
#pragma unroll
    for (int p = 0; p < 4; ++p) {
        int kr = p * 16 + r16;
        float4 f = *(const float4*)&W[(size_t)(kx + kr) * 256 + dx + c4];
        T[kr][c4 + 0] = f2bf(f.x * sc);
        T[kr][c4 + 1] = f2bf(f.y * sc);
        T[kr][c4 + 2] = f2bf(f.z * sc);
        T[kr][c4 + 3] = f2bf(f.w * sc);
    }
    __syncthreads();
    int l16 = tid & 15, nt_loc = (tid >> 4) & 3, quad = (tid >> 6) & 3;
#pragma unroll
    for (int s_loc = 0; s_loc < 2; ++s_loc) {
        int k0 = s_loc * 32 + quad * 8;
        int d_loc = nt_loc * 16 + l16;
        u16 tmp[8];
#pragma unroll
        for (int j = 0; j < 8; ++j) tmp[j] = T[k0 + j][d_loc];
        int d = dx + d_loc;
        int nz = d >> 7, ntg = (d >> 4) & 7;
        int s = (kx >> 5) + s_loc;
        int f = (nz * 8 + s) * 8 + ntg;
        int L = quad * 16 + l16;
        *(uint4*)&wtf[(size_t)mode * 65536 + (size_t)f * 512 + (size_t)L * 8] = *(uint4*)tmp;
    }
    // chores
    if (mode == 1 && kx == 0 && dx == 0) {
        // bf16 multiplicity: 1->0x3F80, 2->0x4000, 4->0x4080; pad/overread -> 0
        for (int i = tid; i < CROWN; i += 256) {
            u16 v = 0;
            if (i < SQ) {
                int rr = i / 56, cc = i - rr * 56;
                int mr = (((rr >= 1) && (rr <= 3)) || ((rr >= 52) && (rr <= 54))) ? 2 : 1;
                int mc = (((cc >= 1) && (cc <= 3)) || ((cc >= 52) && (cc <= 54))) ? 2 : 1;
                int prod = mr * mc;
                v = (prod == 1) ? (u16)0x3F80 : ((prod == 2) ? (u16)0x4000 : (u16)0x4080);
            }
            crow[i] = v;
        }
    }
    if (mode == 2 && kx == 0 && dx == 0) {
        for (int i = tid; i < 512 * 8; i += 256) {
            int row = i >> 3, c16 = i & 7;
            *(uint4*)&vtb[(size_t)row * VT_STRIDE + SQ + c16 * 8] = (uint4){0, 0, 0, 0};
        }
    }
}

// ---------------- kernel 1: projections (dedup: all modes project same 6272 rows) ---
// grid (98, 3 modes, 2 nz). modes 0/1 (Q/K): SWAPPED MFMA operands -> per-lane
// output is row-major [xrow][c] -> packed uint2 stores. mode 2 (V^T): original
// orientation -> [c][kp] paired stores, PRE-SCALED by multiplicity c(kp).
__global__ __launch_bounds__(256, 4) void proj_kernel(const float* __restrict__ x,
                                                      const u16* __restrict__ wtf,
                                                      const float* __restrict__ bq,
                                                      const float* __restrict__ bk,
                                                      const float* __restrict__ bv,
                                                      u16* __restrict__ qout,
                                                      u16* __restrict__ kout,
                                                      u16* __restrict__ vtout) {
    int mode = blockIdx.y, nz = blockIdx.z;
    int mbase = blockIdx.x * 64;
    int tid = threadIdx.x;
    int wave = tid >> 6, quad = (tid >> 4) & 3, l16 = tid & 15;
    const float* bias = (mode == 0) ? bq : ((mode == 1) ? bk : bv);
    float wsc = (mode == 0) ? LOG2E : 1.0f;
    const u16* wf = wtf + (size_t)mode * 65536 + (size_t)nz * 32768 + (size_t)(quad * 16 + l16) * 8;

    int m_a = mbase + wave * 16 + l16;          // x row (identity for all modes now)
    const float* xr = x + (size_t)m_a * 256;

    f32x4 acc[8];
#pragma unroll
    for (int i = 0; i < 8; i++) acc[i] = (f32x4){0.f, 0.f, 0.f, 0.f};

#pragma unroll
    for (int s = 0; s < 8; ++s) {
        float4 f0 = *(const float4*)&xr[s * 32 + quad * 8];
        float4 f1 = *(const float4*)&xr[s * 32 + quad * 8 + 4];
        uint4 aw = (uint4){pack2bf(f0.x, f0.y), pack2bf(f0.z, f0.w),
                           pack2bf(f1.x, f1.y), pack2bf(f1.z, f1.w)};
        bf16x8 af = bc8(aw);
        if (mode == 2) {
#pragma unroll
            for (int nt = 0; nt < 8; nt++) {
                bf16x8 bfrag = *(const bf16x8*)&wf[(s * 8 + nt) * 512];
                acc[nt] = __builtin_amdgcn_mfma_f32_16x16x32_bf16(af, bfrag, acc[nt], 0, 0, 0);
            }
        } else {
#pragma unroll
            for (int nt = 0; nt < 8; nt++) {
                bf16x8 bfrag = *(const bf16x8*)&wf[(s * 8 + nt) * 512];
                acc[nt] = __builtin_amdgcn_mfma_f32_16x16x32_bf16(bfrag, af, acc[nt], 0, 0, 0);
            }
        }
    }

    if (mode == 2) {
        int mrow_base = mbase + wave * 16 + quad * 4;
        float mult[4];
#pragma unroll
        for (int p = 0; p < 4; ++p) {
            int m = mrow_base + p;
            int kp = (m >= SQ) ? m - SQ : m;
            int rr = kp / 56, cc = kp - rr * 56;
            float mr = (((rr >= 1) && (rr <= 3)) || ((rr >= 52) && (rr <= 54))) ? 2.f : 1.f;
            float mc = (((cc >= 1) && (cc <= 3)) || ((cc >= 52) && (cc <= 54))) ? 2.f : 1.f;
            mult[p] = mr * mc;
        }
#pragma unroll
        for (int nt = 0; nt < 8; nt++) {
            int c = nz * 128 + nt * 16 + l16;
            float bvv = bias[c];
#pragma unroll
            for (int p = 0; p < 4; p += 2) {
                int m = mrow_base + p;
                int bb = (m >= SQ) ? 1 : 0;
                int kp = m - bb * SQ;
                unsigned pk = pack2bf((acc[nt][p] + bvv) * mult[p],
                                      (acc[nt][p + 1] + bvv) * mult[p + 1]);
                *(unsigned*)&vtout[(size_t)(bb * 256 + c) * VT_STRIDE + kp] = pk;
            }
        }
    } else {
        u16* outp = (mode == 0) ? qout : kout;
#pragma unroll
        for (int nt = 0; nt < 8; nt++) {
            int c0 = nz * 128 + nt * 16 + quad * 4;
            float4 b4 = *(const float4*)&bias[c0];
            float v0 = acc[nt][0] + b4.x * wsc;
            float v1 = acc[nt][1] + b4.y * wsc;
            float v2 = acc[nt][2] + b4.z * wsc;
            float v3 = acc[nt][3] + b4.w * wsc;
            uint2 pk = (uint2){pack2bf(v0, v1), pack2bf(v2, v3)};
            *(uint2*)&outp[((size_t)m_a << 8) + c0] = pk;
        }
    }
}

// ---------------- kernel 2: flash attention (single-generation, 2-buf, counts-MFMA) -
// grid (16 bh, 49 qsub) = 784 blocks; 39KB LDS + bounds(256,4) -> 4 blocks/CU
// -> 1024 slots >= 784: ALL blocks resident in ONE scheduling generation.
// 25 uniform rounds x 128 keys. No global loads inside the loop (counts staged
// once; multiplicity pre-folded into V and counts). 2 LDS buffers; per-wave
// ownership makes double-buffering race-free; counted vmcnt(4) per round.
__global__ __launch_bounds__(256, 4) void attn_kernel(const u16* __restrict__ qb,
                                                      const u16* __restrict__ kb,
                                                      const u16* __restrict__ vtb,
                                                      const u16* __restrict__ crow,
                                                      const float* __restrict__ x,
                                                      const float* __restrict__ gammap,
                                                      float* __restrict__ out) {
    // bufs at 0, 8192 (u16); counts at 16384 (3584 u16 = 25 rounds x 128 + pad)
    __shared__ __align__(16) u16 S[19968];

    int tid = threadIdx.x;
    int th = tid >> 6, lane = tid & 63, quad = lane >> 4, l16 = lane & 15;
    int bh = blockIdx.x;
    int b = bh >> 3, h = bh & 7;
    int qsub = blockIdx.y * 64;

    bf16x8 qf[4];
#pragma unroll
    for (int i = 0; i < 4; ++i)
        qf[i] = *(const bf16x8*)&qb[((size_t)(b * SQ + qsub + i * 16 + l16) << 8) + h * 32 + quad * 8];

    const u16* kg = kb + ((size_t)(b * SQ) << 8) + h * 32;
    const u16* vg = vtb + (size_t)(b * 256 + h * 32) * VT_STRIDE;

    f32x4 o[4][2], lv[4];
#pragma unroll
    for (int i = 0; i < 4; ++i) {
        o[i][0] = (f32x4){0.f, 0.f, 0.f, 0.f};
        o[i][1] = (f32x4){0.f, 0.f, 0.f, 0.f};
        lv[i]   = (f32x4){0.f, 0.f, 0.f, 0.f};
    }

    auto stage = [&](int r_ch, int buf) {
        u16* base = &S[buf * 8192];
        int kbase = r_ch * 128;
#pragma unroll
        for (int i = 0; i < 2; ++i) {
            int g = th + i * 4;
            int grow = kbase + g * 16 + (lane & 15);
            if (grow > SQ - 1) grow = SQ - 1;
            dma16(kg + ((size_t)grow << 8) + (lane >> 4) * 8, base + g * 512, lane);
            int col = kbase + (2 * g + (lane >> 5)) * 8;
            dma16(vg + (size_t)(lane & 31) * VT_STRIDE + col, base + 4096 + g * 512, lane);
        }
    };

    int tA = th, tB = th + 4;
    int vOffA = tA * 512 + (((quad >> 1) * 32 + l16) << 3) + (quad & 1) * 4;
    int vOffB = tB * 512 + (((quad >> 1) * 32 + l16) << 3) + (quad & 1) * 4;

    auto round_body = [&](int r, int bR) {
        const u16* Kl = &S[bR * 8192];
        const u16* Vl = Kl + 4096;
        const u16* cnt = &S[16384] + r * 128;
        bf16x8 kfA = *(const bf16x8*)&Kl[tA * 512 + lane * 8];
        bf16x8 kfB = *(const bf16x8*)&Kl[tB * 512 + lane * 8];
        // counts B-fragment: j=0..3 -> keys(tA, quad*4+j), j=4..7 -> keys(tB, ...)
        uint2 ca = *(const uint2*)&cnt[tA * 16 + quad * 4];
        uint2 cc = *(const uint2*)&cnt[tB * 16 + quad * 4];
        bf16x8 cf = bc8((uint4){ca.x, ca.y, cc.x, cc.y});
        uint2 wA0 = *(const uint2*)&Vl[vOffA];
        uint2 wB0 = *(const uint2*)&Vl[vOffB];
        uint2 wA1 = *(const uint2*)&Vl[vOffA + 128];
        uint2 wB1 = *(const uint2*)&Vl[vOffB + 128];
        bf16x8 V0 = bc8((uint4){wA0.x, wA0.y, wB0.x, wB0.y});
        bf16x8 V1 = bc8((uint4){wA1.x, wA1.y, wB1.x, wB1.y});

        f32x4 z = (f32x4){0.f, 0.f, 0.f, 0.f};
        f32x4 eA[4], eB[4];
#pragma unroll
        for (int i = 0; i < 4; ++i)
            eA[i] = __builtin_amdgcn_mfma_f32_16x16x32_bf16(kfA, qf[i], z, 0, 0, 0);
#pragma unroll
        for (int i = 0; i < 4; ++i)
            eB[i] = __builtin_amdgcn_mfma_f32_16x16x32_bf16(kfB, qf[i], z, 0, 0, 0);

#pragma unroll
        for (int i = 0; i < 4; ++i) {
            float pA0 = exp2_fast(eA[i][0]), pA1 = exp2_fast(eA[i][1]);
            float pA2 = exp2_fast(eA[i][2]), pA3 = exp2_fast(eA[i][3]);
            float pB0 = exp2_fast(eB[i][0]), pB1 = exp2_fast(eB[i][1]);
            float pB2 = exp2_fast(eB[i][2]), pB3 = exp2_fast(eB[i][3]);
            bf16x8 pa = bc8((uint4){cvtpk(pA0, pA1), cvtpk(pA2, pA3),
                                    cvtpk(pB0, pB1), cvtpk(pB2, pB3)});
            o[i][0] = __builtin_amdgcn_mfma_f32_16x16x32_bf16(pa, V0, o[i][0], 0, 0, 0);
            o[i][1] = __builtin_amdgcn_mfma_f32_16x16x32_bf16(pa, V1, o[i][1], 0, 0, 0);
            lv[i]   = __builtin_amdgcn_mfma_f32_16x16x32_bf16(pa, cf, lv[i], 0, 0, 0);
        }
    };

    // prologue: stage counts (7 x 1KB chunks across 4 waves) + round 0; one barrier
    {
#pragma unroll
        for (int e = 0; e < 2; ++e) {
            int chn = th * 2 + e;
            if (chn < 7)
                dma16(crow + chn * 512 + lane * 8, (char*)&S[16384] + chn * 1024, lane);
        }
    }
    stage(0, 0);
    __syncthreads();           // compiler drains vmcnt(0) before barrier: counts+buf0 ready

    for (int r = 0; r < 25; ++r) {
        if (r + 1 < 25) {
            stage(r + 1, (r + 1) & 1);                         // 4 DMAs into other buf
            asm volatile("s_waitcnt vmcnt(4)" ::: "memory");   // stage(r) complete
        } else {
            asm volatile("s_waitcnt vmcnt(0)" ::: "memory");
        }
        round_body(r, r & 1);
    }

    __syncthreads();                           // all waves done; LDS reusable

    // ---- two-stage merge of 4 t-quarters via LDS ----
    float* mg = (float*)&S[0];
    {
        int slot = ((th & 1) * 64 + lane) * 48;
        if (th >= 2) {
#pragma unroll
            for (int i = 0; i < 4; ++i) {
                *(f32x4*)&mg[slot + i * 8]      = o[i][0];
                *(f32x4*)&mg[slot + i * 8 + 4]  = o[i][1];
                *(f32x4*)&mg[slot + 32 + i * 4] = lv[i];
            }
        }
        __syncthreads();
        if (th < 2) {
#pragma unroll
            for (int i = 0; i < 4; ++i) {
                o[i][0] += *(const f32x4*)&mg[slot + i * 8];
                o[i][1] += *(const f32x4*)&mg[slot + i * 8 + 4];
                lv[i]   += *(const f32x4*)&mg[slot + 32 + i * 4];
            }
        }
        __syncthreads();
    }
    {
        int slot = lane * 48;
        if (th == 1) {
#pragma unroll
            for (int i = 0; i < 4; ++i) {
                *(f32x4*)&mg[slot + i * 8]      = o[i][0];
                *(f32x4*)&mg[slot + i * 8 + 4]  = o[i][1];
                *(f32x4*)&mg[slot + 32 + i * 4] = lv[i];
            }
        }
        __syncthreads();
        if (th == 0) {
            float g = gammap[0];
#pragma unroll
            for (int i = 0; i < 4; ++i) {
                o[i][0] += *(const f32x4*)&mg[slot + i * 8];
                o[i][1] += *(const f32x4*)&mg[slot + i * 8 + 4];
                lv[i]   += *(const f32x4*)&mg[slot + 32 + i * 4];
#pragma unroll
                for (int r2 = 0; r2 < 4; ++r2) {
                    float scl = g / lv[i][r2];     // lv row-aligned with output rows
                    int q = qsub + i * 16 + quad * 4 + r2;
                    size_t base = ((size_t)(b * SQ + q) << 8) + h * 32 + l16;
                    out[base]      = o[i][0][r2] * scl + x[base];
                    out[base + 16] = o[i][1][r2] * scl + x[base + 16];
                }
            }
        }
    }
}

// ---------------- launcher ----------------
extern "C" void kernel_launch(void* const* d_in, const int* in_sizes, int n_in,
                              void* d_out, int out_size, void* d_ws, size_t ws_size,
                              hipStream_t stream) {
    const float* x     = (const float*)d_in[0];
    const float* Wq    = (const float*)d_in[1];
    const float* bq    = (const float*)d_in[2];
    const float* Wk    = (const float*)d_in[3];
    const float* bk    = (const float*)d_in[4];
    const float* Wv    = (const float*)d_in[5];
    const float* bv    = (const float*)d_in[6];
    const float* gamma = (const float*)d_in[7];
    float* out = (float*)d_out;

    u16* ws   = (u16*)d_ws;
    u16* qbuf = ws + WS_Q;
    u16* kbuf = ws + WS_K;
    u16* vtb  = ws + WS_VT;
    u16* wtf  = ws + WS_WT;
    u16* crow = ws + WS_CB;

    wprep_kernel<<<dim3(4, 4, 3), 256, 0, stream>>>(Wq, Wk, Wv, wtf, vtb, crow);
    proj_kernel<<<dim3(98, 3, 2), 256, 0, stream>>>(x, wtf, bq, bk, bv, qbuf, kbuf, vtb);
    attn_kernel<<<dim3(16, 49), 256, 0, stream>>>(qbuf, kbuf, vtb, crow, x, gamma, out);
}